// Round 8
// baseline (176.034 us; speedup 1.0000x reference)
//
#include <hip/hip_runtime.h>

#define NN 50000
#define NE 800000
#define KF 256
#define MF 64

#define NBK 782    // node buckets of 64: ceil(50000/64)
#define HB 49      // hist/scatter blocks
#define EPB 16384  // edges per hist/scatter block (49*16384 >= 800000)
#define GB 782     // gemm blocks (ceil(50000/64))
#define EIDX_CAP (NE + 16 * NBK)  // padded bucket regions

typedef __attribute__((ext_vector_type(8))) short short8;
typedef __attribute__((ext_vector_type(4))) float f32x4;

static __device__ __forceinline__ unsigned short f2bf(float x) {
  unsigned int u = __float_as_uint(x);
  u += 0x7FFF + ((u >> 16) & 1);  // round-nearest-even
  return (unsigned short)(u >> 16);
}
static __device__ __forceinline__ float bf2f(unsigned int u16) {
  return __uint_as_float(u16 << 16);
}

// ------- Prepack W (fp32 [k][n]) into B-fragment-ordered bf16 table --------
__global__ __launch_bounds__(256) void prepack_w(
    const float* __restrict__ W, unsigned short* __restrict__ wtab) {
  const int f = blockIdx.x * 256 + threadIdx.x;  // 0..2047
  const int m = f & 15;
  const int quad = (f >> 4) & 3;
  const int nt = (f >> 6) & 3;
  const int k0i = f >> 8;
  const int n = nt * 16 + m;
  const int kb = k0i * 32 + quad * 8;
  short8 p;
#pragma unroll
  for (int j = 0; j < 8; ++j) p[j] = (short)f2bf(W[(kb + j) * MF + n]);
  *(short8*)(wtab + (size_t)f * 8) = p;
}

// ------- Fused: LDS-free MFMA GEMM (blocks 0..781) + histogram (782..830) --
// A-strip (16 x float4 = 64 VGPRs) fully preloaded BEFORE any convert/MFMA:
// all 16 dwordx4 in flight at once -> latency paid once, not 8x.
__global__ __launch_bounds__(256, 4) void gemm_hist(
    const float* __restrict__ h, const unsigned short* __restrict__ wtab,
    const float* __restrict__ norm, const int* __restrict__ dst,
    unsigned short* __restrict__ hwb, int* __restrict__ histT) {
  __shared__ int hh[NBK];  // hist branch only (3.1 KB)
  const int t = threadIdx.x;

  if (blockIdx.x >= GB) {  // ---- histogram branch ----
    const int hb = blockIdx.x - GB;
    for (int i = t; i < NBK; i += 256) hh[i] = 0;
    __syncthreads();
    const int base = hb * EPB;
#pragma unroll
    for (int i = 0; i < EPB / 256; ++i) {
      const int e = base + i * 256 + t;
      if (e < NE) atomicAdd(&hh[dst[e] >> 6], 1);
    }
    __syncthreads();
    for (int i = t; i < NBK; i += 256) histT[i * 64 + hb] = hh[i];
    return;
  }

  // ---- GEMM branch ----
  const int lane = t & 63;
  const int wv = t >> 6;       // 0..3
  const int m = lane & 15;
  const int quad = lane >> 4;  // 0..3
  const int row0 = blockIdx.x * 64;
  const int arow = row0 + wv * 16 + m;
  const int rowc = (arow < NN) ? arow : (NN - 1);  // clamp; store is guarded
  const float4* ap = (const float4*)(h + (size_t)rowc * KF + quad * 8);

  float4 a[16];
#pragma unroll
  for (int k = 0; k < 8; ++k) {
    a[2 * k] = ap[k * 8];      // k-step stride: 32 floats = 8 float4
    a[2 * k + 1] = ap[k * 8 + 1];
  }

  f32x4 acc[4];
#pragma unroll
  for (int i = 0; i < 4; ++i) acc[i] = (f32x4){0.f, 0.f, 0.f, 0.f};

  const short8* wp = (const short8*)wtab;
#pragma unroll
  for (int k0i = 0; k0i < 8; ++k0i) {
    const float4 a0 = a[2 * k0i];
    const float4 a1 = a[2 * k0i + 1];
    short8 af;
    af[0] = (short)f2bf(a0.x); af[1] = (short)f2bf(a0.y);
    af[2] = (short)f2bf(a0.z); af[3] = (short)f2bf(a0.w);
    af[4] = (short)f2bf(a1.x); af[5] = (short)f2bf(a1.y);
    af[6] = (short)f2bf(a1.z); af[7] = (short)f2bf(a1.w);
    const short8* wk = wp + k0i * 4 * 64 + lane;
#pragma unroll
    for (int nt = 0; nt < 4; ++nt) {
      const short8 bf = wk[nt * 64];  // L1/L2-resident 32 KB table
      acc[nt] = __builtin_amdgcn_mfma_f32_16x16x32_bf16(af, bf, acc[nt], 0, 0, 0);
    }
  }

  // Epilogue: D row = quad*4 + r, col = nt*16 + m
  const int gm0 = row0 + wv * 16 + quad * 4;
  float nrm[4];
#pragma unroll
  for (int r = 0; r < 4; ++r) nrm[r] = (gm0 + r < NN) ? norm[gm0 + r] : 0.f;
#pragma unroll
  for (int nt = 0; nt < 4; ++nt) {
#pragma unroll
    for (int r = 0; r < 4; ++r) {
      const int gm = gm0 + r;
      if (gm < NN) hwb[(size_t)gm * MF + nt * 16 + m] = f2bf(acc[nt][r] * nrm[r]);
    }
  }
}

// ------- Scatter with integrated scan -------------------------------------
__global__ __launch_bounds__(1024) void scatter_scan(
    const int* __restrict__ src, const int* __restrict__ dst,
    const int* __restrict__ histT, int* __restrict__ eidx,
    int* __restrict__ bucketStart, int* __restrict__ bucketCnt) {
  __shared__ int s[1024];
  __shared__ int cur[NBK];
  const int t = threadIdx.x;
  int tot = 0, mine = 0;
  if (t < NBK) {
    const int* hp = histT + t * 64;
#pragma unroll
    for (int b = 0; b < HB; ++b) {
      const int v = hp[b];
      if (b < (int)blockIdx.x) mine += v;
      tot += v;
    }
  }
  const int pad = (tot + 15) & ~15;  // 64 B-align bucket regions
  s[t] = (t < NBK) ? pad : 0;
  __syncthreads();
  for (int off = 1; off < 1024; off <<= 1) {
    const int a = (t >= off) ? s[t - off] : 0;
    __syncthreads();
    s[t] += a;
    __syncthreads();
  }
  if (t < NBK) {
    const int start = s[t] - pad;
    cur[t] = start + mine;
    if (blockIdx.x == 0) {
      bucketStart[t] = start;
      bucketCnt[t] = tot;
    }
  }
  __syncthreads();
  const int base = blockIdx.x * EPB;
#pragma unroll
  for (int i = 0; i < EPB / 1024; ++i) {
    const int e = base + i * 1024 + t;
    if (e < NE) {
      const int d = dst[e];
      const int pos = atomicAdd(&cur[d >> 6], 1);
      eidx[pos] = (src[e] << 6) | (d & 63);
    }
  }
}

// ------- Per-bucket counting sort -> exact per-node CSR --------------------
__global__ __launch_bounds__(256) void csr_sort(
    const int* __restrict__ bucketStart, const int* __restrict__ bucketCnt,
    const int* __restrict__ eidx, int* __restrict__ eidx2,
    int* __restrict__ offs, int* __restrict__ ends) {
  __shared__ int hcnt[64];
  __shared__ int cur[64];
  const int t = threadIdx.x;
  const int g = blockIdx.x;
  const int beg = __builtin_amdgcn_readfirstlane(bucketStart[g]);
  const int cnt = __builtin_amdgcn_readfirstlane(bucketCnt[g]);
  if (t < 64) hcnt[t] = 0;
  __syncthreads();
  for (int i = t; i < cnt; i += 256) atomicAdd(&hcnt[eidx[beg + i] & 63], 1);
  __syncthreads();
  if (t < 64) {
    const int v = hcnt[t];
    int incl = v;
#pragma unroll
    for (int off = 1; off < 64; off <<= 1) {
      const int u = __shfl_up(incl, off, 64);
      if (t >= off) incl += u;
    }
    const int excl = incl - v;
    cur[t] = excl;
    const int vtx = g * 64 + t;
    if (vtx < NN) {
      offs[vtx] = beg + excl;
      ends[vtx] = beg + excl + v;
    }
  }
  __syncthreads();
  for (int i = t; i < cnt; i += 256) {
    const int val = eidx[beg + i];
    const int p = atomicAdd(&cur[val & 63], 1);
    eidx2[beg + p] = val >> 6;
  }
}

// ------- CSR gather: 2 edges per wave-instruction --------------------------
// Lane l: cols (2c, 2c+1), c=l&31, of edge i + (l>>5). uint loads (256 B per
// wave-instr vs 128 B with ushort). One shfl_xor(32) combine at the end.
__global__ __launch_bounds__(256) void gather_finalize(
    const int* __restrict__ offs, const int* __restrict__ ends,
    const int* __restrict__ eidx2, const unsigned short* __restrict__ hwb,
    const float* __restrict__ norm, const float* __restrict__ bias,
    float* __restrict__ out) {
  const int t = threadIdx.x;
  const int lane = t & 63;
  const int v = blockIdx.x * 4 + (t >> 6);
  if (v >= NN) return;
  const int half = lane >> 5;   // 0: even edge, 1: odd edge
  const int c = lane & 31;      // uint column (2 bf16 cols)
  const unsigned int* hw32 = (const unsigned int*)hwb;
  const int beg = __builtin_amdgcn_readfirstlane(offs[v]);
  const int end = __builtin_amdgcn_readfirstlane(ends[v]);

  float ax = 0.f, ay = 0.f;
  int i = beg;
  for (; i + 8 <= end; i += 8) {  // 4 paired loads in flight
    const int e0 = eidx2[i], e1 = eidx2[i + 1], e2 = eidx2[i + 2], e3 = eidx2[i + 3];
    const int e4 = eidx2[i + 4], e5 = eidx2[i + 5], e6 = eidx2[i + 6], e7 = eidx2[i + 7];
    const int s0 = half ? e1 : e0;
    const int s1 = half ? e3 : e2;
    const int s2 = half ? e5 : e4;
    const int s3 = half ? e7 : e6;
    const unsigned int x0 = hw32[(size_t)s0 * 32 + c];
    const unsigned int x1 = hw32[(size_t)s1 * 32 + c];
    const unsigned int x2 = hw32[(size_t)s2 * 32 + c];
    const unsigned int x3 = hw32[(size_t)s3 * 32 + c];
    ax += bf2f(x0 & 0xffffu); ay += bf2f(x0 >> 16);
    ax += bf2f(x1 & 0xffffu); ay += bf2f(x1 >> 16);
    ax += bf2f(x2 & 0xffffu); ay += bf2f(x2 >> 16);
    ax += bf2f(x3 & 0xffffu); ay += bf2f(x3 >> 16);
  }
  for (; i + 2 <= end; i += 2) {
    const int e0 = eidx2[i], e1 = eidx2[i + 1];
    const int s0 = half ? e1 : e0;
    const unsigned int x0 = hw32[(size_t)s0 * 32 + c];
    ax += bf2f(x0 & 0xffffu); ay += bf2f(x0 >> 16);
  }
  if (i < end && half == 0) {  // odd tail: only even-half lanes contribute
    const unsigned int x0 = hw32[(size_t)eidx2[i] * 32 + c];
    ax += bf2f(x0 & 0xffffu); ay += bf2f(x0 >> 16);
  }
  // combine halves: lanes l and l^32 hold same cols, different edges
  ax += __shfl_xor(ax, 32);
  ay += __shfl_xor(ay, 32);
  if (half == 0) {
    const float n = norm[v];
    const float2 b = ((const float2*)bias)[c];
    float2 o;
    o.x = fmaxf(ax * n + b.x, 0.f);
    o.y = fmaxf(ay * n + b.y, 0.f);
    ((float2*)(out + (size_t)v * MF))[c] = o;
  }
}

extern "C" void kernel_launch(void* const* d_in, const int* in_sizes, int n_in,
                              void* d_out, int out_size, void* d_ws, size_t ws_size,
                              hipStream_t stream) {
  const float* h = (const float*)d_in[0];
  const float* norm = (const float*)d_in[1];
  const float* W = (const float*)d_in[2];
  const float* bias = (const float*)d_in[3];
  const int* src = (const int*)d_in[4];
  const int* dst = (const int*)d_in[5];
  float* out = (float*)d_out;

  unsigned short* hwb = (unsigned short*)d_ws;       // NN*MF bf16 (6.4 MB)
  unsigned short* wtab = hwb + (size_t)NN * MF;      // 16384 bf16 (32 KB)
  int* histT = (int*)(wtab + 16384);                 // NBK*64
  int* bucketStart = histT + NBK * 64;               // NBK (+pad)
  int* bucketCnt = bucketStart + ((NBK + 15) & ~15);
  int* offs = bucketCnt + ((NBK + 15) & ~15);        // NN
  int* ends = offs + ((NN + 15) & ~15);              // NN
  int* eidx = ends + ((NN + 15) & ~15);              // EIDX_CAP
  int* eidx2 = eidx + ((EIDX_CAP + 15) & ~15);       // EIDX_CAP
  const size_t need =
      ((size_t)NN * MF / 2 + 8192 + NBK * 64 + 2 * ((NBK + 15) & ~15) +
       2 * ((NN + 15) & ~15) + 2 * ((EIDX_CAP + 15) & ~15)) * 4;
  if (ws_size < need) return;

  prepack_w<<<8, 256, 0, stream>>>(W, wtab);
  gemm_hist<<<GB + HB, 256, 0, stream>>>(h, wtab, norm, dst, hwb, histT);
  scatter_scan<<<HB, 1024, 0, stream>>>(src, dst, histT, eidx, bucketStart, bucketCnt);
  csr_sort<<<NBK, 256, 0, stream>>>(bucketStart, bucketCnt, eidx, eidx2, offs, ends);
  gather_finalize<<<(NN + 3) / 4, 256, 0, stream>>>(offs, ends, eidx2, hwb, norm, bias, out);
}

// Round 9
// 164.373 us; speedup vs baseline: 1.0709x; 1.0709x over previous
//
#include <hip/hip_runtime.h>

#define NN 50000
#define NE 800000
#define KF 256
#define MF 64

#define NBK 782    // node buckets of 64: ceil(50000/64)
#define HB 49      // hist/scatter blocks
#define EPB 16384  // edges per hist/scatter block (49*16384 >= 800000)
#define GB 782     // gemm blocks (ceil(50000/64))
#define EIDX_CAP (NE + 16 * NBK)  // padded bucket regions

typedef __attribute__((ext_vector_type(8))) short short8;
typedef __attribute__((ext_vector_type(4))) float f32x4;

static __device__ __forceinline__ unsigned short f2bf(float x) {
  unsigned int u = __float_as_uint(x);
  u += 0x7FFF + ((u >> 16) & 1);  // round-nearest-even
  return (unsigned short)(u >> 16);
}
static __device__ __forceinline__ float bf2f(unsigned short u) {
  return __uint_as_float(((unsigned int)u) << 16);
}

// ------- Edge histogram: per-(block,bucket), transposed histT --------------
__global__ __launch_bounds__(1024) void edge_hist(
    const int* __restrict__ dst, int* __restrict__ histT) {
  __shared__ int hh[NBK];
  const int t = threadIdx.x;
  for (int i = t; i < NBK; i += 1024) hh[i] = 0;
  __syncthreads();
  const int base = blockIdx.x * EPB;
#pragma unroll
  for (int i = 0; i < EPB / 1024; ++i) {
    const int e = base + i * 1024 + t;
    if (e < NE) atomicAdd(&hh[dst[e] >> 6], 1);
  }
  __syncthreads();
  for (int i = t; i < NBK; i += 1024) histT[i * 64 + blockIdx.x] = hh[i];
}

// ------- Prepack W (fp32 [k][n]) into B-fragment-ordered bf16 table --------
__global__ __launch_bounds__(256) void prepack_w(
    const float* __restrict__ W, unsigned short* __restrict__ wtab) {
  const int f = blockIdx.x * 256 + threadIdx.x;  // 0..2047
  const int m = f & 15;
  const int quad = (f >> 4) & 3;
  const int nt = (f >> 6) & 3;
  const int k0i = f >> 8;
  const int n = nt * 16 + m;
  const int kb = k0i * 32 + quad * 8;
  short8 p;
#pragma unroll
  for (int j = 0; j < 8; ++j) p[j] = (short)f2bf(W[(kb + j) * MF + n]);
  *(short8*)(wtab + (size_t)f * 8) = p;
}

// ------- Scatter with integrated scan -------------------------------------
__global__ __launch_bounds__(1024) void scatter_scan(
    const int* __restrict__ src, const int* __restrict__ dst,
    const int* __restrict__ histT, int* __restrict__ eidx,
    int* __restrict__ bucketStart, int* __restrict__ bucketCnt) {
  __shared__ int s[1024];
  __shared__ int cur[NBK];
  const int t = threadIdx.x;
  int tot = 0, mine = 0;
  if (t < NBK) {
    const int* hp = histT + t * 64;
#pragma unroll
    for (int b = 0; b < HB; ++b) {
      const int v = hp[b];
      if (b < (int)blockIdx.x) mine += v;
      tot += v;
    }
  }
  const int pad = (tot + 15) & ~15;  // 64 B-align bucket regions
  s[t] = (t < NBK) ? pad : 0;
  __syncthreads();
  for (int off = 1; off < 1024; off <<= 1) {
    const int a = (t >= off) ? s[t - off] : 0;
    __syncthreads();
    s[t] += a;
    __syncthreads();
  }
  if (t < NBK) {
    const int start = s[t] - pad;
    cur[t] = start + mine;
    if (blockIdx.x == 0) {
      bucketStart[t] = start;
      bucketCnt[t] = tot;
    }
  }
  __syncthreads();
  const int base = blockIdx.x * EPB;
#pragma unroll
  for (int i = 0; i < EPB / 1024; ++i) {
    const int e = base + i * 1024 + t;
    if (e < NE) {
      const int d = dst[e];
      const int pos = atomicAdd(&cur[d >> 6], 1);
      eidx[pos] = (src[e] << 6) | (d & 63);
    }
  }
}

// ------- Per-bucket counting sort -> exact per-node CSR --------------------
__global__ __launch_bounds__(256) void csr_sort(
    const int* __restrict__ bucketStart, const int* __restrict__ bucketCnt,
    const int* __restrict__ eidx, int* __restrict__ eidx2,
    int* __restrict__ offs, int* __restrict__ ends) {
  __shared__ int hcnt[64];
  __shared__ int cur[64];
  const int t = threadIdx.x;
  const int g = blockIdx.x;
  const int beg = __builtin_amdgcn_readfirstlane(bucketStart[g]);
  const int cnt = __builtin_amdgcn_readfirstlane(bucketCnt[g]);
  if (t < 64) hcnt[t] = 0;
  __syncthreads();
  for (int i = t; i < cnt; i += 256) atomicAdd(&hcnt[eidx[beg + i] & 63], 1);
  __syncthreads();
  if (t < 64) {
    const int v = hcnt[t];
    int incl = v;
#pragma unroll
    for (int off = 1; off < 64; off <<= 1) {
      const int u = __shfl_up(incl, off, 64);
      if (t >= off) incl += u;
    }
    const int excl = incl - v;
    cur[t] = excl;
    const int vtx = g * 64 + t;
    if (vtx < NN) {
      offs[vtx] = beg + excl;
      ends[vtx] = beg + excl + v;
    }
  }
  __syncthreads();
  for (int i = t; i < cnt; i += 256) {
    const int val = eidx[beg + i];
    const int p = atomicAdd(&cur[val & 63], 1);
    eidx2[beg + p] = val >> 6;
  }
}

// ------- LDS-free MFMA GEMM, batched A-preload pinned by sched_barrier -----
// hwb[i][j] = bf16((h@W)[i][j] * norm[i]). All 16 A-loads issue before any
// convert/MFMA (sched_barrier(0) fences stop the compiler from sinking
// them back into the k-loop -> latency paid once, not 8x).
__global__ __launch_bounds__(256, 4) void gemm_mfma(
    const float* __restrict__ h, const unsigned short* __restrict__ wtab,
    const float* __restrict__ norm, unsigned short* __restrict__ hwb) {
  const int t = threadIdx.x;
  const int lane = t & 63;
  const int wv = t >> 6;       // 0..3
  const int m = lane & 15;
  const int quad = lane >> 4;  // 0..3
  const int row0 = blockIdx.x * 64;
  const int arow = row0 + wv * 16 + m;
  const int rowc = (arow < NN) ? arow : (NN - 1);  // clamp; store is guarded
  const float4* ap = (const float4*)(h + (size_t)rowc * KF + quad * 8);

  float4 a[16];
#pragma unroll
  for (int k = 0; k < 8; ++k) {
    a[2 * k] = ap[k * 8];      // k-step stride: 32 floats = 8 float4
    a[2 * k + 1] = ap[k * 8 + 1];
  }
  __builtin_amdgcn_sched_barrier(0);  // all 16 loads stay above this line

  short8 af[8];
#pragma unroll
  for (int k = 0; k < 8; ++k) {
    const float4 a0 = a[2 * k];
    const float4 a1 = a[2 * k + 1];
    af[k][0] = (short)f2bf(a0.x); af[k][1] = (short)f2bf(a0.y);
    af[k][2] = (short)f2bf(a0.z); af[k][3] = (short)f2bf(a0.w);
    af[k][4] = (short)f2bf(a1.x); af[k][5] = (short)f2bf(a1.y);
    af[k][6] = (short)f2bf(a1.z); af[k][7] = (short)f2bf(a1.w);
  }
  __builtin_amdgcn_sched_barrier(0);  // converts complete before MFMA loop

  f32x4 acc[4];
#pragma unroll
  for (int i = 0; i < 4; ++i) acc[i] = (f32x4){0.f, 0.f, 0.f, 0.f};

  const short8* wp = (const short8*)wtab;
#pragma unroll
  for (int k0i = 0; k0i < 8; ++k0i) {
    const short8* wk = wp + k0i * 4 * 64 + lane;
#pragma unroll
    for (int nt = 0; nt < 4; ++nt) {
      const short8 bf = wk[nt * 64];  // L1/L2-resident 32 KB table
      acc[nt] = __builtin_amdgcn_mfma_f32_16x16x32_bf16(af[k0i], bf, acc[nt], 0, 0, 0);
    }
  }

  // Epilogue: D row = quad*4 + r, col = nt*16 + m
  const int gm0 = row0 + wv * 16 + quad * 4;
  float nrm[4];
#pragma unroll
  for (int r = 0; r < 4; ++r) nrm[r] = (gm0 + r < NN) ? norm[gm0 + r] : 0.f;
#pragma unroll
  for (int nt = 0; nt < 4; ++nt) {
#pragma unroll
    for (int r = 0; r < 4; ++r) {
      const int gm = gm0 + r;
      if (gm < NN) hwb[(size_t)gm * MF + nt * 16 + m] = f2bf(acc[nt][r] * nrm[r]);
    }
  }
}

// ------- CSR gather (bf16 rows, 8-deep) + fused epilogue -------------------
__global__ __launch_bounds__(256) void gather_finalize(
    const int* __restrict__ offs, const int* __restrict__ ends,
    const int* __restrict__ eidx2, const unsigned short* __restrict__ hwb,
    const float* __restrict__ norm, const float* __restrict__ bias,
    float* __restrict__ out) {
  const int t = threadIdx.x;
  const int lane = t & 63;
  const int v = blockIdx.x * 4 + (t >> 6);
  if (v >= NN) return;
  const int beg = __builtin_amdgcn_readfirstlane(offs[v]);
  const int end = __builtin_amdgcn_readfirstlane(ends[v]);
  float acc = 0.f;
  int i = beg;
  for (; i + 8 <= end; i += 8) {  // 8 row-loads in flight
    const int s0 = eidx2[i], s1 = eidx2[i + 1], s2 = eidx2[i + 2], s3 = eidx2[i + 3];
    const int s4 = eidx2[i + 4], s5 = eidx2[i + 5], s6 = eidx2[i + 6], s7 = eidx2[i + 7];
    const unsigned short x0 = hwb[(size_t)s0 * MF + lane];
    const unsigned short x1 = hwb[(size_t)s1 * MF + lane];
    const unsigned short x2 = hwb[(size_t)s2 * MF + lane];
    const unsigned short x3 = hwb[(size_t)s3 * MF + lane];
    const unsigned short x4 = hwb[(size_t)s4 * MF + lane];
    const unsigned short x5 = hwb[(size_t)s5 * MF + lane];
    const unsigned short x6 = hwb[(size_t)s6 * MF + lane];
    const unsigned short x7 = hwb[(size_t)s7 * MF + lane];
    acc += bf2f(x0); acc += bf2f(x1); acc += bf2f(x2); acc += bf2f(x3);
    acc += bf2f(x4); acc += bf2f(x5); acc += bf2f(x6); acc += bf2f(x7);
  }
  for (; i + 2 <= end; i += 2) {
    const int s0 = eidx2[i], s1 = eidx2[i + 1];
    const unsigned short x0 = hwb[(size_t)s0 * MF + lane];
    const unsigned short x1 = hwb[(size_t)s1 * MF + lane];
    acc += bf2f(x0); acc += bf2f(x1);
  }
  if (i < end) acc += bf2f(hwb[(size_t)eidx2[i] * MF + lane]);
  const float o = acc * norm[v] + bias[lane];
  out[(size_t)v * MF + lane] = fmaxf(o, 0.f);
}

extern "C" void kernel_launch(void* const* d_in, const int* in_sizes, int n_in,
                              void* d_out, int out_size, void* d_ws, size_t ws_size,
                              hipStream_t stream) {
  const float* h = (const float*)d_in[0];
  const float* norm = (const float*)d_in[1];
  const float* W = (const float*)d_in[2];
  const float* bias = (const float*)d_in[3];
  const int* src = (const int*)d_in[4];
  const int* dst = (const int*)d_in[5];
  float* out = (float*)d_out;

  unsigned short* hwb = (unsigned short*)d_ws;       // NN*MF bf16 (6.4 MB)
  unsigned short* wtab = hwb + (size_t)NN * MF;      // 16384 bf16 (32 KB)
  int* histT = (int*)(wtab + 16384);                 // NBK*64
  int* bucketStart = histT + NBK * 64;               // NBK (+pad)
  int* bucketCnt = bucketStart + ((NBK + 15) & ~15);
  int* offs = bucketCnt + ((NBK + 15) & ~15);        // NN
  int* ends = offs + ((NN + 15) & ~15);              // NN
  int* eidx = ends + ((NN + 15) & ~15);              // EIDX_CAP
  int* eidx2 = eidx + ((EIDX_CAP + 15) & ~15);       // EIDX_CAP
  const size_t need =
      ((size_t)NN * MF / 2 + 8192 + NBK * 64 + 2 * ((NBK + 15) & ~15) +
       2 * ((NN + 15) & ~15) + 2 * ((EIDX_CAP + 15) & ~15)) * 4;
  if (ws_size < need) return;

  // Edge pipeline first (BW-light, latency-tolerant: absorbs the starved
  // front window); BW-heavy GEMM late; gather last.
  edge_hist<<<HB, 1024, 0, stream>>>(dst, histT);
  prepack_w<<<8, 256, 0, stream>>>(W, wtab);
  scatter_scan<<<HB, 1024, 0, stream>>>(src, dst, histT, eidx, bucketStart, bucketCnt);
  csr_sort<<<NBK, 256, 0, stream>>>(bucketStart, bucketCnt, eidx, eidx2, offs, ends);
  gemm_mfma<<<GB, 256, 0, stream>>>(h, wtab, norm, hwb);
  gather_finalize<<<(NN + 3) / 4, 256, 0, stream>>>(offs, ends, eidx2, hwb, norm, bias, out);
}